// Round 5
// baseline (19.975 us; speedup 1.0000x reference)
//
#include <hip/hip_runtime.h>

#define BB 4
#define LL 1024
#define NPOS (BB*LL)
#define TI 8
#define JPT 2
// pair kernel: 256 threads/block, each thread 2 consecutive j's -> 512 j's/block
// grid = (LL/512, LL/TI, BB) = (2, 128, 4) = 1024 blocks -> 4 blocks/CU

typedef float f32x4 __attribute__((ext_vector_type(4)));

#define NEG_LOG2E -1.4426950408889634f
#if __has_builtin(__builtin_amdgcn_exp2f)
#define EXP2(x) __builtin_amdgcn_exp2f(x)
#else
#define EXP2(x) __expf((x) * 0.6931471805599453f)
#endif

__device__ __forceinline__ void ffn4(float x,
    const float* __restrict__ W1, const float* __restrict__ b1,
    const float* __restrict__ W2, const float* __restrict__ b2, float out[4]) {
    float h[4];
#pragma unroll
    for (int d = 0; d < 4; ++d) h[d] = fmaxf(fmaf(x, W1[d], b1[d]), 0.0f);
#pragma unroll
    for (int j = 0; j < 4; ++j) {
        float a = b2[j];
#pragma unroll
        for (int d = 0; d < 4; ++d) a = fmaf(h[d], W2[d * 4 + j], a);
        out[j] = fmaxf(a, 0.0f);
    }
}

// Per-position tables (SoA float4, 4096 entries each):
//   S2 = (sg+eps)^2 ; C = f*cos(2pi*pv*x) ; S = f*sin(2pi*pv*x), f = be*sqrt(sg+eps)
__global__ void precompute_kernel(const float* __restrict__ t,
    const float* __restrict__ Wp1, const float* __restrict__ bp1,
    const float* __restrict__ Wp2, const float* __restrict__ bp2,
    const float* __restrict__ Ws1, const float* __restrict__ bs1,
    const float* __restrict__ Ws2, const float* __restrict__ bs2,
    const float* __restrict__ Wb1, const float* __restrict__ bb1,
    const float* __restrict__ Wb2, const float* __restrict__ bb2,
    f32x4* __restrict__ S2, f32x4* __restrict__ C, f32x4* __restrict__ S)
{
    int p = blockIdx.x * blockDim.x + threadIdx.x;
    if (p >= NPOS) return;
    float x = t[p];
    float pv[4], sg[4], bv[4];
    ffn4(x, Wp1, bp1, Wp2, bp2, pv);
    ffn4(x, Ws1, bs1, Ws2, bs2, sg);
    ffn4(x, Wb1, bb1, Wb2, bb2, bv);
    f32x4 s2o, co, so;
#pragma unroll
    for (int d = 0; d < 4; ++d) {
        float qp = 6.283185307179586f * pv[d] * x;
        float s, c;
        __sincosf(qp, &s, &c);
        float sq = sg[d] + 1e-6f;
        float f  = bv[d] * sqrtf(sq);
        s2o[d] = sq * sq;
        co[d]  = f * c;
        so[d]  = f * s;
    }
    S2[p] = s2o; C[p] = co; S[p] = so;
}

__device__ __forceinline__ float dot_term(f32x4 s2i, f32x4 s2j,
                                          f32x4 ci, f32x4 cj,
                                          f32x4 si, f32x4 sj, float ntd2l)
{
    f32x4 den = s2i + s2j;
    f32x4 rs;
#pragma unroll
    for (int k = 0; k < 4; ++k) rs[k] = rsqrtf(den[k]);
    f32x4 arg = (ntd2l * rs) * rs;       // -log2e*td^2 / den
    f32x4 e;
#pragma unroll
    for (int k = 0; k < 4; ++k) e[k] = EXP2(arg[k]);
    f32x4 cv = __builtin_elementwise_fma(ci, cj, si * sj);
    f32x4 m = (rs * e) * cv;
    return (m.x + m.y) + (m.z + m.w);
}

__global__ __launch_bounds__(256) void pair_kernel(const float* __restrict__ t,
    const f32x4* __restrict__ S2, const f32x4* __restrict__ C,
    const f32x4* __restrict__ S, float* __restrict__ out)
{
    __shared__ f32x4 sh_s2[TI], sh_c[TI], sh_s[TI];
    __shared__ float sh_t[TI];

    const int tid = threadIdx.x;
    const int b   = blockIdx.z;
    const int i0  = blockIdx.y * TI;
    const int j0  = blockIdx.x * (256 * JPT) + tid * JPT;

    if (tid < TI) {
        int p = b * LL + i0 + tid;
        sh_s2[tid] = S2[p];
        sh_c[tid]  = C[p] * 1.41421356237309505f;  // sqrt(2) folded into i side
        sh_s[tid]  = S[p] * 1.41421356237309505f;
        sh_t[tid]  = t[p];
    }

    const int pj = b * LL + j0;
    float tj0 = t[pj], tj1 = t[pj + 1];
    f32x4 s2j0 = S2[pj], s2j1 = S2[pj + 1];
    f32x4 cj0  = C[pj],  cj1  = C[pj + 1];
    f32x4 sj0  = S[pj],  sj1  = S[pj + 1];

    __syncthreads();

    float* obase = out + ((size_t)b * LL + i0) * LL + j0;

#pragma unroll
    for (int ii = 0; ii < TI; ++ii) {
        f32x4 s2i = sh_s2[ii], ci = sh_c[ii], si = sh_s[ii];
        float tiv = sh_t[ii];
        float td0 = tiv - tj0, td1 = tiv - tj1;
        float r0 = dot_term(s2i, s2j0, ci, cj0, si, sj0, td0 * td0 * NEG_LOG2E);
        float r1 = dot_term(s2i, s2j1, ci, cj1, si, sj1, td1 * td1 * NEG_LOG2E);
        *reinterpret_cast<float2*>(obase + (size_t)ii * LL) = make_float2(r0, r1);
    }
}

extern "C" void kernel_launch(void* const* d_in, const int* in_sizes, int n_in,
                              void* d_out, int out_size, void* d_ws, size_t ws_size,
                              hipStream_t stream) {
    const float* t   = (const float*)d_in[0];
    const float* Wp1 = (const float*)d_in[1];
    const float* bp1 = (const float*)d_in[2];
    const float* Wp2 = (const float*)d_in[3];
    const float* bp2 = (const float*)d_in[4];
    const float* Ws1 = (const float*)d_in[5];
    const float* bs1 = (const float*)d_in[6];
    const float* Ws2 = (const float*)d_in[7];
    const float* bs2 = (const float*)d_in[8];
    const float* Wb1 = (const float*)d_in[9];
    const float* bb1 = (const float*)d_in[10];
    const float* Wb2 = (const float*)d_in[11];
    const float* bb2 = (const float*)d_in[12];
    float* out = (float*)d_out;

    f32x4* S2 = (f32x4*)d_ws;
    f32x4* C  = S2 + NPOS;
    f32x4* S  = C + NPOS;

    hipLaunchKernelGGL(precompute_kernel, dim3(NPOS / 64), dim3(64), 0, stream,
                       t, Wp1, bp1, Wp2, bp2, Ws1, bs1, Ws2, bs2,
                       Wb1, bb1, Wb2, bb2, S2, C, S);

    dim3 grid(LL / (256 * JPT), LL / TI, BB);  // (2, 128, 4)
    hipLaunchKernelGGL(pair_kernel, grid, dim3(256), 0, stream,
                       t, S2, C, S, out);
}

// Round 6
// 17.717 us; speedup vs baseline: 1.1275x; 1.1275x over previous
//
#include <hip/hip_runtime.h>

#define BB 4
#define LL 1024
#define TI 32
#define JPT 2
// 256 threads/block, each thread 2 consecutive j's -> block covers 512 j's.
// grid = (LL/512, LL/TI, BB) = (2, 32, 4) = 256 blocks -> 1 block/CU.
// Evidence: R3(TI=16, 2 blk/CU)=16.6us, R4(TI=8, 4 blk/CU)=17.3us -> extra
// occupancy bought nothing (delta == redundancy delta). TI=32 halves the
// j-side posdata redundancy (4*LL^2/TI evals: 262K -> 131K).

typedef float f32x2 __attribute__((ext_vector_type(2)));
typedef float f32x4 __attribute__((ext_vector_type(4)));

#define NEG_LOG2E -1.4426950408889634f
#if __has_builtin(__builtin_amdgcn_exp2f)
#define EXP2(x) __builtin_amdgcn_exp2f(x)
#else
#define EXP2(x) __expf((x) * 0.6931471805599453f)
#endif

__device__ __forceinline__ void ffn4(float x,
    const float* __restrict__ W1, const float* __restrict__ b1,
    const float* __restrict__ W2, const float* __restrict__ b2, float out[4]) {
    float h[4];
#pragma unroll
    for (int d = 0; d < 4; ++d) h[d] = fmaxf(fmaf(x, W1[d], b1[d]), 0.0f);
#pragma unroll
    for (int j = 0; j < 4; ++j) {
        float a = b2[j];
#pragma unroll
        for (int d = 0; d < 4; ++d) a = fmaf(h[d], W2[d * 4 + j], a);
        out[j] = fmaxf(a, 0.0f);
    }
}

// s2 = (sg+eps)^2 ; c = f*cos(2pi*pv*x) ; s = f*sin(2pi*pv*x)
// f = be*sqrt(sg+eps) (* sqrt(2) on the i side, folded once)
template<bool R2>
__device__ __forceinline__ void posdata(float x,
    const float* __restrict__ Wp1, const float* __restrict__ bp1,
    const float* __restrict__ Wp2, const float* __restrict__ bp2,
    const float* __restrict__ Ws1, const float* __restrict__ bs1,
    const float* __restrict__ Ws2, const float* __restrict__ bs2,
    const float* __restrict__ Wb1, const float* __restrict__ bb1,
    const float* __restrict__ Wb2, const float* __restrict__ bb2,
    f32x4& s2o, f32x4& co, f32x4& so)
{
    float pv[4], sg[4], bv[4];
    ffn4(x, Wp1, bp1, Wp2, bp2, pv);
    ffn4(x, Ws1, bs1, Ws2, bs2, sg);
    ffn4(x, Wb1, bb1, Wb2, bb2, bv);
#pragma unroll
    for (int d = 0; d < 4; ++d) {
        float qp = 6.283185307179586f * pv[d] * x;
        float s, c;
        __sincosf(qp, &s, &c);
        float sq = sg[d] + 1e-6f;
        float f  = bv[d] * sqrtf(sq);
        if (R2) f *= 1.41421356237309505f;
        s2o[d] = sq * sq;
        co[d]  = f * c;
        so[d]  = f * s;
    }
}

__device__ __forceinline__ f32x2 pair_term(f32x2 s2i, f32x2 s2j,
                                           f32x2 ci, f32x2 cj,
                                           f32x2 si, f32x2 sj,
                                           f32x2 ntd2l, f32x2 acc)
{
    f32x2 den = s2i + s2j;
    f32x2 rs; rs.x = rsqrtf(den.x); rs.y = rsqrtf(den.y);
    f32x2 arg = (ntd2l * rs) * rs;            // -log2e*td^2 / den
    f32x2 e; e.x = EXP2(arg.x); e.y = EXP2(arg.y);
    f32x2 cv = __builtin_elementwise_fma(ci, cj, si * sj);
    return __builtin_elementwise_fma(rs * e, cv, acc);
}

__global__ __launch_bounds__(256) void fused_kernel(const float* __restrict__ t,
    const float* __restrict__ Wp1, const float* __restrict__ bp1,
    const float* __restrict__ Wp2, const float* __restrict__ bp2,
    const float* __restrict__ Ws1, const float* __restrict__ bs1,
    const float* __restrict__ Ws2, const float* __restrict__ bs2,
    const float* __restrict__ Wb1, const float* __restrict__ bb1,
    const float* __restrict__ Wb2, const float* __restrict__ bb2,
    float* __restrict__ out)
{
    __shared__ f32x4 sh_s2[TI], sh_c[TI], sh_s[TI];
    __shared__ float sh_t[TI];

    const int tid = threadIdx.x;
    const int b   = blockIdx.z;
    const int i0  = blockIdx.y * TI;
    const int j0  = blockIdx.x * (256 * JPT) + tid * JPT;

    // i-tile (32 rows) staged by threads 0..31
    if (tid < TI) {
        float xi = t[b * LL + i0 + tid];
        f32x4 s2i, ci, si;
        posdata<true>(xi, Wp1, bp1, Wp2, bp2, Ws1, bs1, Ws2, bs2,
                      Wb1, bb1, Wb2, bb2, s2i, ci, si);
        sh_t[tid]  = xi;
        sh_s2[tid] = s2i;
        sh_c[tid]  = ci;
        sh_s[tid]  = si;
    }

    // per-thread j data (2 columns) in registers
    float tj0 = t[b * LL + j0];
    float tj1 = t[b * LL + j0 + 1];
    f32x4 s2j4[2], cj4[2], sj4[2];
    posdata<false>(tj0, Wp1, bp1, Wp2, bp2, Ws1, bs1, Ws2, bs2,
                   Wb1, bb1, Wb2, bb2, s2j4[0], cj4[0], sj4[0]);
    posdata<false>(tj1, Wp1, bp1, Wp2, bp2, Ws1, bs1, Ws2, bs2,
                   Wb1, bb1, Wb2, bb2, s2j4[1], cj4[1], sj4[1]);

    f32x2 s2j_lo[2], s2j_hi[2], cj_lo[2], cj_hi[2], sj_lo[2], sj_hi[2];
#pragma unroll
    for (int jj = 0; jj < JPT; ++jj) {
        s2j_lo[jj] = f32x2{s2j4[jj].x, s2j4[jj].y};
        s2j_hi[jj] = f32x2{s2j4[jj].z, s2j4[jj].w};
        cj_lo[jj]  = f32x2{cj4[jj].x,  cj4[jj].y};
        cj_hi[jj]  = f32x2{cj4[jj].z,  cj4[jj].w};
        sj_lo[jj]  = f32x2{sj4[jj].x,  sj4[jj].y};
        sj_hi[jj]  = f32x2{sj4[jj].z,  sj4[jj].w};
    }
    const float tj[2] = {tj0, tj1};

    __syncthreads();

    float* obase = out + ((size_t)b * LL + i0) * LL + j0;

#pragma unroll 8
    for (int ii = 0; ii < TI; ++ii) {
        f32x4 s2i4 = sh_s2[ii], ci4 = sh_c[ii], si4 = sh_s[ii];
        float tiv = sh_t[ii];
        f32x2 s2i_lo = f32x2{s2i4.x, s2i4.y}, s2i_hi = f32x2{s2i4.z, s2i4.w};
        f32x2 ci_lo  = f32x2{ci4.x,  ci4.y},  ci_hi  = f32x2{ci4.z,  ci4.w};
        f32x2 si_lo  = f32x2{si4.x,  si4.y},  si_hi  = f32x2{si4.z,  si4.w};
        float res[JPT];
#pragma unroll
        for (int jj = 0; jj < JPT; ++jj) {
            float td = tiv - tj[jj];
            float n  = td * td * NEG_LOG2E;
            f32x2 ntd2l; ntd2l.x = n; ntd2l.y = n;
            f32x2 acc; acc.x = 0.0f; acc.y = 0.0f;
            acc = pair_term(s2i_lo, s2j_lo[jj], ci_lo, cj_lo[jj],
                            si_lo,  sj_lo[jj],  ntd2l, acc);
            acc = pair_term(s2i_hi, s2j_hi[jj], ci_hi, cj_hi[jj],
                            si_hi,  sj_hi[jj],  ntd2l, acc);
            res[jj] = acc.x + acc.y;
        }
        *reinterpret_cast<float2*>(obase + (size_t)ii * LL) = make_float2(res[0], res[1]);
    }
}

extern "C" void kernel_launch(void* const* d_in, const int* in_sizes, int n_in,
                              void* d_out, int out_size, void* d_ws, size_t ws_size,
                              hipStream_t stream) {
    const float* t   = (const float*)d_in[0];
    const float* Wp1 = (const float*)d_in[1];
    const float* bp1 = (const float*)d_in[2];
    const float* Wp2 = (const float*)d_in[3];
    const float* bp2 = (const float*)d_in[4];
    const float* Ws1 = (const float*)d_in[5];
    const float* bs1 = (const float*)d_in[6];
    const float* Ws2 = (const float*)d_in[7];
    const float* bs2 = (const float*)d_in[8];
    const float* Wb1 = (const float*)d_in[9];
    const float* bb1 = (const float*)d_in[10];
    const float* Wb2 = (const float*)d_in[11];
    const float* bb2 = (const float*)d_in[12];
    float* out = (float*)d_out;

    dim3 grid(LL / (256 * JPT), LL / TI, BB);  // (2, 32, 4) = 256 blocks
    hipLaunchKernelGGL(fused_kernel, grid, dim3(256), 0, stream,
                       t, Wp1, bp1, Wp2, bp2, Ws1, bs1, Ws2, bs2,
                       Wb1, bb1, Wb2, bb2, out);
}

// Round 7
// 16.688 us; speedup vs baseline: 1.1969x; 1.0616x over previous
//
#include <hip/hip_runtime.h>

#define BB 4
#define LL 1024
#define TI 16
#define JPT 2
// Optimum from R3-R6 sweep: TI=16, JPT=2, grid (2,64,4)=512 blocks -> 2 blk/CU.
// R4: 4 blk/CU + 2x redundancy = +0.7us. R6: 1 blk/CU + 0.5x redundancy = +1.1us.
// This round: R3 config + exp2-direct (saves log2e muls, shortens rsqrt->exp
// chain) + f32x2-native LDS rows (no lo/hi unpack in the inner loop).

typedef float f32x2 __attribute__((ext_vector_type(2)));

#define NEG_LOG2E -1.4426950408889634f
#if __has_builtin(__builtin_amdgcn_exp2f)
#define EXP2(x) __builtin_amdgcn_exp2f(x)
#else
#define EXP2(x) __expf((x) * 0.6931471805599453f)
#endif

struct PosData {
    f32x2 s2l, s2h;   // (sg+eps)^2, dims 0-1 / 2-3
    f32x2 cl,  ch;    // f*cos(2pi*pv*x)
    f32x2 sl,  sh2;   // f*sin(2pi*pv*x)
};

struct PosRow {
    PosData d;
    float   tt;
    float   pad;
};

__device__ __forceinline__ void ffn4(float x,
    const float* __restrict__ W1, const float* __restrict__ b1,
    const float* __restrict__ W2, const float* __restrict__ b2, float out[4]) {
    float h[4];
#pragma unroll
    for (int d = 0; d < 4; ++d) h[d] = fmaxf(fmaf(x, W1[d], b1[d]), 0.0f);
#pragma unroll
    for (int j = 0; j < 4; ++j) {
        float a = b2[j];
#pragma unroll
        for (int d = 0; d < 4; ++d) a = fmaf(h[d], W2[d * 4 + j], a);
        out[j] = fmaxf(a, 0.0f);
    }
}

// f = be*sqrt(sg+eps) (* sqrt(2) on the i side, folded once)
template<bool R2>
__device__ __forceinline__ PosData posdata(float x,
    const float* __restrict__ Wp1, const float* __restrict__ bp1,
    const float* __restrict__ Wp2, const float* __restrict__ bp2,
    const float* __restrict__ Ws1, const float* __restrict__ bs1,
    const float* __restrict__ Ws2, const float* __restrict__ bs2,
    const float* __restrict__ Wb1, const float* __restrict__ bb1,
    const float* __restrict__ Wb2, const float* __restrict__ bb2)
{
    float pv[4], sg[4], bv[4];
    ffn4(x, Wp1, bp1, Wp2, bp2, pv);
    ffn4(x, Ws1, bs1, Ws2, bs2, sg);
    ffn4(x, Wb1, bb1, Wb2, bb2, bv);
    float cc[4], ss[4], s2[4];
#pragma unroll
    for (int d = 0; d < 4; ++d) {
        float qp = 6.283185307179586f * pv[d] * x;
        float s, c;
        __sincosf(qp, &s, &c);
        float sq = sg[d] + 1e-6f;
        float f  = bv[d] * sqrtf(sq);
        if (R2) f *= 1.41421356237309505f;
        s2[d] = sq * sq;
        cc[d] = f * c;
        ss[d] = f * s;
    }
    PosData r;
    r.s2l = f32x2{s2[0], s2[1]}; r.s2h = f32x2{s2[2], s2[3]};
    r.cl  = f32x2{cc[0], cc[1]}; r.ch  = f32x2{cc[2], cc[3]};
    r.sl  = f32x2{ss[0], ss[1]}; r.sh2 = f32x2{ss[2], ss[3]};
    return r;
}

__device__ __forceinline__ f32x2 pair_term(f32x2 s2i, f32x2 s2j,
                                           f32x2 ci, f32x2 cj,
                                           f32x2 si, f32x2 sj,
                                           f32x2 ntd2l, f32x2 acc)
{
    f32x2 den = s2i + s2j;
    f32x2 rs; rs.x = rsqrtf(den.x); rs.y = rsqrtf(den.y);
    f32x2 arg = (ntd2l * rs) * rs;            // -log2e*td^2 / den
    f32x2 e; e.x = EXP2(arg.x); e.y = EXP2(arg.y);
    f32x2 cv = __builtin_elementwise_fma(ci, cj, si * sj);
    return __builtin_elementwise_fma(rs * e, cv, acc);
}

__global__ __launch_bounds__(256) void fused_kernel(const float* __restrict__ t,
    const float* __restrict__ Wp1, const float* __restrict__ bp1,
    const float* __restrict__ Wp2, const float* __restrict__ bp2,
    const float* __restrict__ Ws1, const float* __restrict__ bs1,
    const float* __restrict__ Ws2, const float* __restrict__ bs2,
    const float* __restrict__ Wb1, const float* __restrict__ bb1,
    const float* __restrict__ Wb2, const float* __restrict__ bb2,
    float* __restrict__ out)
{
    __shared__ PosRow rows[TI];

    const int tid = threadIdx.x;
    const int b   = blockIdx.z;
    const int i0  = blockIdx.y * TI;
    const int j0  = blockIdx.x * (256 * JPT) + tid * JPT;

    if (tid < TI) {
        float xi = t[b * LL + i0 + tid];
        rows[tid].d  = posdata<true>(xi, Wp1, bp1, Wp2, bp2, Ws1, bs1, Ws2, bs2,
                                     Wb1, bb1, Wb2, bb2);
        rows[tid].tt = xi;
    }

    const float2 tj2 = *reinterpret_cast<const float2*>(&t[b * LL + j0]);
    const float tj[JPT] = {tj2.x, tj2.y};
    PosData jd[JPT];
#pragma unroll
    for (int jj = 0; jj < JPT; ++jj) {
        jd[jj] = posdata<false>(tj[jj], Wp1, bp1, Wp2, bp2, Ws1, bs1, Ws2, bs2,
                                Wb1, bb1, Wb2, bb2);
    }

    __syncthreads();

    float* obase = out + ((size_t)b * LL + i0) * LL + j0;

#pragma unroll
    for (int ii = 0; ii < TI; ++ii) {
        PosRow rw = rows[ii];
        float res[JPT];
#pragma unroll
        for (int jj = 0; jj < JPT; ++jj) {
            float td = rw.tt - tj[jj];
            float n  = td * td * NEG_LOG2E;
            f32x2 ntd2l; ntd2l.x = n; ntd2l.y = n;
            f32x2 acc; acc.x = 0.0f; acc.y = 0.0f;
            acc = pair_term(rw.d.s2l, jd[jj].s2l, rw.d.cl, jd[jj].cl,
                            rw.d.sl,  jd[jj].sl,  ntd2l, acc);
            acc = pair_term(rw.d.s2h, jd[jj].s2h, rw.d.ch, jd[jj].ch,
                            rw.d.sh2, jd[jj].sh2, ntd2l, acc);
            res[jj] = acc.x + acc.y;
        }
        *reinterpret_cast<float2*>(obase + (size_t)ii * LL) = make_float2(res[0], res[1]);
    }
}

extern "C" void kernel_launch(void* const* d_in, const int* in_sizes, int n_in,
                              void* d_out, int out_size, void* d_ws, size_t ws_size,
                              hipStream_t stream) {
    const float* t   = (const float*)d_in[0];
    const float* Wp1 = (const float*)d_in[1];
    const float* bp1 = (const float*)d_in[2];
    const float* Wp2 = (const float*)d_in[3];
    const float* bp2 = (const float*)d_in[4];
    const float* Ws1 = (const float*)d_in[5];
    const float* bs1 = (const float*)d_in[6];
    const float* Ws2 = (const float*)d_in[7];
    const float* bs2 = (const float*)d_in[8];
    const float* Wb1 = (const float*)d_in[9];
    const float* bb1 = (const float*)d_in[10];
    const float* Wb2 = (const float*)d_in[11];
    const float* bb2 = (const float*)d_in[12];
    float* out = (float*)d_out;

    dim3 grid(LL / (256 * JPT), LL / TI, BB);  // (2, 64, 4) = 512 blocks
    hipLaunchKernelGGL(fused_kernel, grid, dim3(256), 0, stream,
                       t, Wp1, bp1, Wp2, bp2, Ws1, bs1, Ws2, bs2,
                       Wb1, bb1, Wb2, bb2, out);
}